// Round 1
// baseline (503.254 us; speedup 1.0000x reference)
//
#include <hip/hip_runtime.h>
#include <hip/hip_cooperative_groups.h>
#include <math.h>

namespace cg = cooperative_groups;

#define NMAX 4096
#define N4   (NMAX/4)
#define CH4  (N4/4)     // visc velocity staging chunk (in float4)

// n assumed multiple of 16 (reference: N=4096).

constexpr float RADIUS       = 0.1f;
constexpr float DT           = 1.0f / 60.0f;
constexpr float MAX_VEL      = 3.0f;               // 0.5*0.1/DT
constexpr float VISCOSITY    = 60.0f;
constexpr float DENSITY_REST = 17510.1f;
constexpr float STIFFNESS    = 2.99e-11f;
constexpr float EPS          = 1e-8f;
constexpr float SPIKY_C      = (float)(15.0 / (3.14159265358979323846 * 1e-6)); // 15/(pi*R^6)

__device__ __forceinline__ float elem(const float4& v, int c) {
    return reinterpret_cast<const float*>(&v)[c];
}

// Compute predicted positions for the whole system into LDS (SoA float4).
__device__ __forceinline__ void predict_to_lds(const float4* __restrict__ locs4,
                                               const float4* __restrict__ vel4,
                                               float4* sx, float4* sy, float4* sz,
                                               int n4, int tid, int nthreads) {
    for (int g = tid; g < n4; g += nthreads) {
        float lo[12], ve[12];
        *(float4*)&lo[0] = locs4[3*g];   *(float4*)&lo[4] = locs4[3*g+1]; *(float4*)&lo[8] = locs4[3*g+2];
        *(float4*)&ve[0] = vel4[3*g];    *(float4*)&ve[4] = vel4[3*g+1];  *(float4*)&ve[8] = vel4[3*g+2];
        float X[4], Y[4], Z[4];
#pragma unroll
        for (int p = 0; p < 4; ++p) {
            float vx = ve[3*p], vy = ve[3*p+1] - 9.8f * DT, vz = ve[3*p+2];
            float vv = sqrtf(vx*vx + vy*vy + vz*vz);
            float s  = fminf(MAX_VEL / (vv + 1e-4f), 1.0f);
            X[p] = lo[3*p]   + DT * vx * s;
            Y[p] = lo[3*p+1] + DT * vy * s;
            Z[p] = lo[3*p+2] + DT * vz * s;
        }
        sx[g] = make_float4(X[0], X[1], X[2], X[3]);
        sy[g] = make_float4(Y[0], Y[1], Y[2], Y[3]);
        sz[g] = make_float4(Z[0], Z[1], Z[2], Z[3]);
    }
}

// rho body (2 particles/wave): writes pre-scaled L = -3C*lam for i0, i0+1.
__device__ __forceinline__ void rho_body2(const float4* sx, const float4* sy, const float4* sz,
                                          float* __restrict__ lam, int n4, int i0, int lane) {
    const float* fx = (const float*)sx; const float* fy = (const float*)sy; const float* fz = (const float*)sz;
    const float xi0 = fx[i0],   yi0 = fy[i0],   zi0 = fz[i0];
    const float xi1 = fx[i0+1], yi1 = fy[i0+1], zi1 = fz[i0+1];
    float S0 = 0.f, S1 = 0.f;
    for (int k = lane; k < n4; k += 64) {
        float4 X = sx[k], Y = sy[k], Z = sz[k];
#pragma unroll
        for (int c = 0; c < 4; ++c) {
            float xj = elem(X,c), yj = elem(Y,c), zj = elem(Z,c);
            {
                float dx = xi0-xj, dy = yi0-yj, dz = zi0-zj;
                float d2 = fmaf(dx,dx,EPS); d2 = fmaf(dy,dy,d2); d2 = fmaf(dz,dz,d2);
                float t  = fmaxf(RADIUS - __builtin_amdgcn_sqrtf(d2), 0.f);
                S0 = fmaf(t*t, t, S0);
            }
            {
                float dx = xi1-xj, dy = yi1-yj, dz = zi1-zj;
                float d2 = fmaf(dx,dx,EPS); d2 = fmaf(dy,dy,d2); d2 = fmaf(dz,dz,d2);
                float t  = fmaxf(RADIUS - __builtin_amdgcn_sqrtf(d2), 0.f);
                S1 = fmaf(t*t, t, S1);
            }
        }
    }
    for (int off = 32; off > 0; off >>= 1) {
        S0 += __shfl_down(S0, off);
        S1 += __shfl_down(S1, off);
    }
    if (lane == 0) {
        const float ts  = RADIUS - __builtin_amdgcn_sqrtf(EPS);  // exact self-term
        const float TS3 = ts*ts*ts;
        const float k3  = 3.f * SPIKY_C * STIFFNESS;             // L = -3C*lam
        lam[i0]   = k3 * (SPIKY_C * (S0 - TS3) - DENSITY_REST);
        lam[i0+1] = k3 * (SPIKY_C * (S1 - TS3) - DENSITY_REST);
    }
}

// delta body (2 particles/wave). Writes new pred (SoA) and optionally final outputs.
__device__ __forceinline__ void delta_body2(const float4* sx, const float4* sy, const float4* sz,
                                            const float4* sl,
                                            float* __restrict__ qx, float* __restrict__ qy, float* __restrict__ qz,
                                            const float* __restrict__ locs,
                                            float* __restrict__ out_pred,
                                            float* __restrict__ vnx, float* __restrict__ vny, float* __restrict__ vnz,
                                            int n4, int i0, int lane) {
    const float* fx = (const float*)sx; const float* fy = (const float*)sy;
    const float* fz = (const float*)sz; const float* fl = (const float*)sl;
    const float xi0 = fx[i0],   yi0 = fy[i0],   zi0 = fz[i0],   L0 = fl[i0];
    const float xi1 = fx[i0+1], yi1 = fy[i0+1], zi1 = fz[i0+1], L1 = fl[i0+1];
    float ax0=0.f, ay0=0.f, az0=0.f, ax1=0.f, ay1=0.f, az1=0.f;
    for (int k = lane; k < n4; k += 64) {
        float4 X = sx[k], Y = sy[k], Z = sz[k], L = sl[k];
#pragma unroll
        for (int c = 0; c < 4; ++c) {
            float xj = elem(X,c), yj = elem(Y,c), zj = elem(Z,c), Lj = elem(L,c);
            {
                float dx = xi0-xj, dy = yi0-yj, dz = zi0-zj;
                float d2 = fmaf(dx,dx,EPS); d2 = fmaf(dy,dy,d2); d2 = fmaf(dz,dz,d2);
                float rinv = __builtin_amdgcn_rsqf(d2);
                float t  = fmaxf(RADIUS - d2*rinv, 0.f);
                float cf = (L0 + Lj) * (t*t) * rinv;
                ax0 = fmaf(cf, dx, ax0); ay0 = fmaf(cf, dy, ay0); az0 = fmaf(cf, dz, az0);
            }
            {
                float dx = xi1-xj, dy = yi1-yj, dz = zi1-zj;
                float d2 = fmaf(dx,dx,EPS); d2 = fmaf(dy,dy,d2); d2 = fmaf(dz,dz,d2);
                float rinv = __builtin_amdgcn_rsqf(d2);
                float t  = fmaxf(RADIUS - d2*rinv, 0.f);
                float cf = (L1 + Lj) * (t*t) * rinv;
                ax1 = fmaf(cf, dx, ax1); ay1 = fmaf(cf, dy, ay1); az1 = fmaf(cf, dz, az1);
            }
        }
    }
    for (int off = 32; off > 0; off >>= 1) {
        ax0 += __shfl_down(ax0, off); ay0 += __shfl_down(ay0, off); az0 += __shfl_down(az0, off);
        ax1 += __shfl_down(ax1, off); ay1 += __shfl_down(ay1, off); az1 += __shfl_down(az1, off);
    }
    if (lane == 0) {
        float nx0 = xi0+ax0, ny0 = yi0+ay0, nz0 = zi0+az0;
        float nx1 = xi1+ax1, ny1 = yi1+ay1, nz1 = zi1+az1;
        qx[i0] = nx0; qy[i0] = ny0; qz[i0] = nz0;
        qx[i0+1] = nx1; qy[i0+1] = ny1; qz[i0+1] = nz1;
        if (out_pred) {
#pragma unroll
            for (int u = 0; u < 2; ++u) {
                int i = i0 + u;
                float nx_ = u ? nx1 : nx0, ny_ = u ? ny1 : ny0, nz_ = u ? nz1 : nz0;
                out_pred[3*i+0] = nx_; out_pred[3*i+1] = ny_; out_pred[3*i+2] = nz_;
                vnx[i] = (nx_ - locs[3*i+0]) * (1.0f/DT);
                vny[i] = (ny_ - locs[3*i+1]) * (1.0f/DT);
                vnz[i] = (nz_ - locs[3*i+2]) * (1.0f/DT);
            }
        }
    }
}

// ---------------- single fused cooperative kernel ----------------
// 256 blocks x 512 threads (8 waves), 2 particles/wave, 64 KB static LDS,
// all blocks co-resident (1 block/CU). Grid-wide exchange via grid.sync().

__global__ __launch_bounds__(512, 2) void k_fused(const float4* __restrict__ locs4,
                                                  const float4* __restrict__ vel4,
                                                  const float* __restrict__ locs,
                                                  float* __restrict__ px, float* __restrict__ py,
                                                  float* __restrict__ pz,
                                                  float* __restrict__ lam,
                                                  float* __restrict__ vnx, float* __restrict__ vny,
                                                  float* __restrict__ vnz,
                                                  float* __restrict__ out, int n) {
    cg::grid_group grid = cg::this_grid();
    __shared__ float4 sx[N4], sy[N4], sz[N4], sl[N4];   // 64 KB
    const int n4   = n >> 2;
    const int lane = threadIdx.x & 63;
    const int i0   = blockIdx.x * 16 + (threadIdx.x >> 6) * 2;

    // predict: every block builds the full predicted-position copy in LDS
    // (no global exchange needed for iteration 1's rho).
    predict_to_lds(locs4, vel4, sx, sy, sz, n4, threadIdx.x, 512);
    __syncthreads();

    for (int it = 0; it < 3; ++it) {
        const bool last = (it == 2);

        // rho: LDS pred -> L[i0..i0+1] (global)
        rho_body2(sx, sy, sz, lam, n4, i0, lane);
        __threadfence();
        grid.sync();

        // stage L into LDS
        for (int idx = threadIdx.x; idx < n4; idx += 512) sl[idx] = ((const float4*)lam)[idx];
        __syncthreads();

        // delta: LDS pred + LDS L -> new pred for own particles (global SoA);
        // on last iteration also emit out_pred and new_vel.
        delta_body2(sx, sy, sz, sl, px, py, pz,
                    last ? locs : nullptr, last ? out : nullptr, vnx, vny, vnz,
                    n4, i0, lane);
        __threadfence();
        grid.sync();

        // re-stage updated pred into LDS (used by next rho, or by visc)
        for (int idx = threadIdx.x; idx < n4; idx += 512) {
            sx[idx] = ((const float4*)px)[idx];
            sy[idx] = ((const float4*)py)[idx];
            sz[idx] = ((const float4*)pz)[idx];
        }
        __syncthreads();
    }

    // ---- XSPH viscosity on final positions (pred already in sx/sy/sz) ----
    const float* fpx = (const float*)sx; const float* fpy = (const float*)sy; const float* fpz = (const float*)sz;
    const float xi0 = fpx[i0],   yi0 = fpy[i0],   zi0 = fpz[i0];
    const float xi1 = fpx[i0+1], yi1 = fpy[i0+1], zi1 = fpz[i0+1];
    const float vix0 = vnx[i0],   viy0 = vny[i0],   viz0 = vnz[i0];
    const float vix1 = vnx[i0+1], viy1 = vny[i0+1], viz1 = vnz[i0+1];
    float ws0=0.f, ax0=0.f, ay0=0.f, az0=0.f;
    float ws1=0.f, ax1=0.f, ay1=0.f, az1=0.f;
    const float4* vx4 = (const float4*)vnx;
    const float4* vy4 = (const float4*)vny;
    const float4* vz4 = (const float4*)vnz;
    for (int ch = 0; ch < 4; ++ch) {
        __syncthreads();
        for (int idx = threadIdx.x; idx < CH4; idx += 512) {
            sl[idx]         = vx4[ch*CH4+idx];
            sl[CH4+idx]     = vy4[ch*CH4+idx];
            sl[2*CH4+idx]   = vz4[ch*CH4+idx];
        }
        __syncthreads();
        for (int k = lane; k < CH4; k += 64) {
            float4 X = sx[ch*CH4+k], Y = sy[ch*CH4+k], Z = sz[ch*CH4+k];
            float4 VX = sl[k], VY = sl[CH4+k], VZ = sl[2*CH4+k];
#pragma unroll
            for (int c = 0; c < 4; ++c) {
                float xj = elem(X,c), yj = elem(Y,c), zj = elem(Z,c);
                float vxj = elem(VX,c), vyj = elem(VY,c), vzj = elem(VZ,c);
                {
                    float dx = xi0-xj, dy = yi0-yj, dz = zi0-zj;
                    float d2 = fmaf(dx,dx,EPS); d2 = fmaf(dy,dy,d2); d2 = fmaf(dz,dz,d2);
                    float t  = fmaxf(RADIUS - __builtin_amdgcn_sqrtf(d2), 0.f);
                    float w  = t*t*t;
                    ws0 += w;
                    ax0 = fmaf(w, vxj, ax0); ay0 = fmaf(w, vyj, ay0); az0 = fmaf(w, vzj, az0);
                }
                {
                    float dx = xi1-xj, dy = yi1-yj, dz = zi1-zj;
                    float d2 = fmaf(dx,dx,EPS); d2 = fmaf(dy,dy,d2); d2 = fmaf(dz,dz,d2);
                    float t  = fmaxf(RADIUS - __builtin_amdgcn_sqrtf(d2), 0.f);
                    float w  = t*t*t;
                    ws1 += w;
                    ax1 = fmaf(w, vxj, ax1); ay1 = fmaf(w, vyj, ay1); az1 = fmaf(w, vzj, az1);
                }
            }
        }
    }
    for (int off = 32; off > 0; off >>= 1) {
        ws0 += __shfl_down(ws0, off); ax0 += __shfl_down(ax0, off);
        ay0 += __shfl_down(ay0, off); az0 += __shfl_down(az0, off);
        ws1 += __shfl_down(ws1, off); ax1 += __shfl_down(ax1, off);
        ay1 += __shfl_down(ay1, off); az1 += __shfl_down(az1, off);
    }
    if (lane == 0) {
        constexpr float K = VISCOSITY * DT / DENSITY_REST;
        const float KC = K * SPIKY_C;   // C folded here
#pragma unroll
        for (int u = 0; u < 2; ++u) {
            int i = i0 + u;
            float vix = (u ? vix1 : vix0), viy = (u ? viy1 : viy0), viz = (u ? viz1 : viz0);
            float sw  = (u ? ws1 : ws0);
            float sax = (u ? ax1 : ax0), say = (u ? ay1 : ay0), saz = (u ? az1 : az0);
            float nvx = vix + KC * (sax - sw * vix);
            float nvy = viy + KC * (say - sw * viy);
            float nvz = viz + KC * (saz - sw * viz);
            float vv = sqrtf(nvx*nvx + nvy*nvy + nvz*nvz);
            float s  = fminf(MAX_VEL / (vv + 1e-4f), 1.0f);
            out[3*n + 3*i + 0] = nvx * s;
            out[3*n + 3*i + 1] = nvy * s;
            out[3*n + 3*i + 2] = nvz * s;
        }
    }
}

extern "C" void kernel_launch(void* const* d_in, const int* in_sizes, int n_in,
                              void* d_out, int out_size, void* d_ws, size_t ws_size,
                              hipStream_t stream) {
    const float* locs = (const float*)d_in[0];
    const float* vel  = (const float*)d_in[1];
    const float4* locs4 = (const float4*)locs;
    const float4* vel4  = (const float4*)vel;
    float* out = (float*)d_out;
    int n = in_sizes[0] / 3;

    float* w = (float*)d_ws;
    float* px  = w;        float* py  = px + n;   float* pz  = py + n;
    float* lam = pz + n;
    float* vnx = lam + n;  float* vny = vnx + n;  float* vnz = vny + n;

    int nb = n / 16;   // 8 waves/block, 2 particles/wave -> 256 blocks for n=4096

    void* args[] = { (void*)&locs4, (void*)&vel4, (void*)&locs,
                     (void*)&px, (void*)&py, (void*)&pz,
                     (void*)&lam,
                     (void*)&vnx, (void*)&vny, (void*)&vnz,
                     (void*)&out, (void*)&n };
    hipLaunchCooperativeKernel((void*)k_fused, dim3(nb), dim3(512), args, 0, stream);
}

// Round 2
// 174.399 us; speedup vs baseline: 2.8857x; 2.8857x over previous
//
#include <hip/hip_runtime.h>
#include <math.h>

#define NMAX 4096
#define N4   (NMAX/4)
#define CH4  (N4/4)     // visc velocity staging chunk (in float4)

// n assumed multiple of 16 (reference: N=4096).

constexpr float RADIUS       = 0.1f;
constexpr float DT           = 1.0f / 60.0f;
constexpr float MAX_VEL      = 3.0f;               // 0.5*0.1/DT
constexpr float VISCOSITY    = 60.0f;
constexpr float DENSITY_REST = 17510.1f;
constexpr float STIFFNESS    = 2.99e-11f;
constexpr float EPS          = 1e-8f;
constexpr float SPIKY_C      = (float)(15.0 / (3.14159265358979323846 * 1e-6)); // 15/(pi*R^6)

__device__ __forceinline__ float elem(const float4& v, int c) {
    return reinterpret_cast<const float*>(&v)[c];
}

// Device-coherent (sc1) scalar store: write-through past the non-coherent
// local L2 so peer XCDs can see it after the barrier, without buffer_wbl2.
__device__ __forceinline__ void store_dc(float* p, float v) {
    __hip_atomic_store(p, v, __ATOMIC_RELAXED, __HIP_MEMORY_SCOPE_AGENT);
}

// Monotonic grid barrier. Counter must start at 0 (memset by host).
// Phase p waits for counter >= p * gridDim.x. Assumes co-resident grid
// (cooperative launch). Data written with store_dc is visible after exit.
__device__ __forceinline__ void grid_barrier(unsigned int* bar, unsigned int target) {
    __syncthreads();   // drains each wave's vmcnt (incl. sc1 stores) before arrive
    if (threadIdx.x == 0) {
        __hip_atomic_fetch_add(bar, 1u, __ATOMIC_RELAXED, __HIP_MEMORY_SCOPE_AGENT);
        while (__hip_atomic_load(bar, __ATOMIC_RELAXED, __HIP_MEMORY_SCOPE_AGENT) < target) {
            __builtin_amdgcn_s_sleep(2);
        }
        __builtin_amdgcn_fence(__ATOMIC_ACQUIRE, "agent");   // buffer_inv sc1
    }
    __syncthreads();
}

// Compute predicted positions for the whole system into LDS (SoA float4).
__device__ __forceinline__ void predict_to_lds(const float4* __restrict__ locs4,
                                               const float4* __restrict__ vel4,
                                               float4* sx, float4* sy, float4* sz,
                                               int n4, int tid, int nthreads) {
    for (int g = tid; g < n4; g += nthreads) {
        float lo[12], ve[12];
        *(float4*)&lo[0] = locs4[3*g];   *(float4*)&lo[4] = locs4[3*g+1]; *(float4*)&lo[8] = locs4[3*g+2];
        *(float4*)&ve[0] = vel4[3*g];    *(float4*)&ve[4] = vel4[3*g+1];  *(float4*)&ve[8] = vel4[3*g+2];
        float X[4], Y[4], Z[4];
#pragma unroll
        for (int p = 0; p < 4; ++p) {
            float vx = ve[3*p], vy = ve[3*p+1] - 9.8f * DT, vz = ve[3*p+2];
            float vv = sqrtf(vx*vx + vy*vy + vz*vz);
            float s  = fminf(MAX_VEL / (vv + 1e-4f), 1.0f);
            X[p] = lo[3*p]   + DT * vx * s;
            Y[p] = lo[3*p+1] + DT * vy * s;
            Z[p] = lo[3*p+2] + DT * vz * s;
        }
        sx[g] = make_float4(X[0], X[1], X[2], X[3]);
        sy[g] = make_float4(Y[0], Y[1], Y[2], Y[3]);
        sz[g] = make_float4(Z[0], Z[1], Z[2], Z[3]);
    }
}

// rho body (2 particles/wave): writes pre-scaled L = -3C*lam for i0, i0+1.
__device__ __forceinline__ void rho_body2(const float4* sx, const float4* sy, const float4* sz,
                                          float* __restrict__ lam, int n4, int i0, int lane) {
    const float* fx = (const float*)sx; const float* fy = (const float*)sy; const float* fz = (const float*)sz;
    const float xi0 = fx[i0],   yi0 = fy[i0],   zi0 = fz[i0];
    const float xi1 = fx[i0+1], yi1 = fy[i0+1], zi1 = fz[i0+1];
    float S0 = 0.f, S1 = 0.f;
    for (int k = lane; k < n4; k += 64) {
        float4 X = sx[k], Y = sy[k], Z = sz[k];
#pragma unroll
        for (int c = 0; c < 4; ++c) {
            float xj = elem(X,c), yj = elem(Y,c), zj = elem(Z,c);
            {
                float dx = xi0-xj, dy = yi0-yj, dz = zi0-zj;
                float d2 = fmaf(dx,dx,EPS); d2 = fmaf(dy,dy,d2); d2 = fmaf(dz,dz,d2);
                float t  = fmaxf(RADIUS - __builtin_amdgcn_sqrtf(d2), 0.f);
                S0 = fmaf(t*t, t, S0);
            }
            {
                float dx = xi1-xj, dy = yi1-yj, dz = zi1-zj;
                float d2 = fmaf(dx,dx,EPS); d2 = fmaf(dy,dy,d2); d2 = fmaf(dz,dz,d2);
                float t  = fmaxf(RADIUS - __builtin_amdgcn_sqrtf(d2), 0.f);
                S1 = fmaf(t*t, t, S1);
            }
        }
    }
    for (int off = 32; off > 0; off >>= 1) {
        S0 += __shfl_down(S0, off);
        S1 += __shfl_down(S1, off);
    }
    if (lane == 0) {
        const float ts  = RADIUS - __builtin_amdgcn_sqrtf(EPS);  // exact self-term
        const float TS3 = ts*ts*ts;
        const float k3  = 3.f * SPIKY_C * STIFFNESS;             // L = -3C*lam
        store_dc(&lam[i0],   k3 * (SPIKY_C * (S0 - TS3) - DENSITY_REST));
        store_dc(&lam[i0+1], k3 * (SPIKY_C * (S1 - TS3) - DENSITY_REST));
    }
}

// delta body (2 particles/wave). Writes new pred (SoA, device-coherent) and
// optionally final outputs.
__device__ __forceinline__ void delta_body2(const float4* sx, const float4* sy, const float4* sz,
                                            const float4* sl,
                                            float* __restrict__ qx, float* __restrict__ qy, float* __restrict__ qz,
                                            const float* __restrict__ locs,
                                            float* __restrict__ out_pred,
                                            float* __restrict__ vnx, float* __restrict__ vny, float* __restrict__ vnz,
                                            int n4, int i0, int lane) {
    const float* fx = (const float*)sx; const float* fy = (const float*)sy;
    const float* fz = (const float*)sz; const float* fl = (const float*)sl;
    const float xi0 = fx[i0],   yi0 = fy[i0],   zi0 = fz[i0],   L0 = fl[i0];
    const float xi1 = fx[i0+1], yi1 = fy[i0+1], zi1 = fz[i0+1], L1 = fl[i0+1];
    float ax0=0.f, ay0=0.f, az0=0.f, ax1=0.f, ay1=0.f, az1=0.f;
    for (int k = lane; k < n4; k += 64) {
        float4 X = sx[k], Y = sy[k], Z = sz[k], L = sl[k];
#pragma unroll
        for (int c = 0; c < 4; ++c) {
            float xj = elem(X,c), yj = elem(Y,c), zj = elem(Z,c), Lj = elem(L,c);
            {
                float dx = xi0-xj, dy = yi0-yj, dz = zi0-zj;
                float d2 = fmaf(dx,dx,EPS); d2 = fmaf(dy,dy,d2); d2 = fmaf(dz,dz,d2);
                float rinv = __builtin_amdgcn_rsqf(d2);
                float t  = fmaxf(RADIUS - d2*rinv, 0.f);
                float cf = (L0 + Lj) * (t*t) * rinv;
                ax0 = fmaf(cf, dx, ax0); ay0 = fmaf(cf, dy, ay0); az0 = fmaf(cf, dz, az0);
            }
            {
                float dx = xi1-xj, dy = yi1-yj, dz = zi1-zj;
                float d2 = fmaf(dx,dx,EPS); d2 = fmaf(dy,dy,d2); d2 = fmaf(dz,dz,d2);
                float rinv = __builtin_amdgcn_rsqf(d2);
                float t  = fmaxf(RADIUS - d2*rinv, 0.f);
                float cf = (L1 + Lj) * (t*t) * rinv;
                ax1 = fmaf(cf, dx, ax1); ay1 = fmaf(cf, dy, ay1); az1 = fmaf(cf, dz, az1);
            }
        }
    }
    for (int off = 32; off > 0; off >>= 1) {
        ax0 += __shfl_down(ax0, off); ay0 += __shfl_down(ay0, off); az0 += __shfl_down(az0, off);
        ax1 += __shfl_down(ax1, off); ay1 += __shfl_down(ay1, off); az1 += __shfl_down(az1, off);
    }
    if (lane == 0) {
        float nx0 = xi0+ax0, ny0 = yi0+ay0, nz0 = zi0+az0;
        float nx1 = xi1+ax1, ny1 = yi1+ay1, nz1 = zi1+az1;
        store_dc(&qx[i0], nx0);   store_dc(&qy[i0], ny0);   store_dc(&qz[i0], nz0);
        store_dc(&qx[i0+1], nx1); store_dc(&qy[i0+1], ny1); store_dc(&qz[i0+1], nz1);
        if (out_pred) {
#pragma unroll
            for (int u = 0; u < 2; ++u) {
                int i = i0 + u;
                float nx_ = u ? nx1 : nx0, ny_ = u ? ny1 : ny0, nz_ = u ? nz1 : nz0;
                out_pred[3*i+0] = nx_; out_pred[3*i+1] = ny_; out_pred[3*i+2] = nz_;
                store_dc(&vnx[i], (nx_ - locs[3*i+0]) * (1.0f/DT));
                store_dc(&vny[i], (ny_ - locs[3*i+1]) * (1.0f/DT));
                store_dc(&vnz[i], (nz_ - locs[3*i+2]) * (1.0f/DT));
            }
        }
    }
}

// ---------------- single fused cooperative kernel ----------------
// 256 blocks x 512 threads (8 waves), 2 particles/wave, 64 KB static LDS,
// all blocks co-resident (1 block/CU). Grid-wide exchange via custom barrier.

__global__ __launch_bounds__(512, 2) void k_fused(const float4* __restrict__ locs4,
                                                  const float4* __restrict__ vel4,
                                                  const float* __restrict__ locs,
                                                  float* __restrict__ px, float* __restrict__ py,
                                                  float* __restrict__ pz,
                                                  float* __restrict__ lam,
                                                  float* __restrict__ vnx, float* __restrict__ vny,
                                                  float* __restrict__ vnz,
                                                  float* __restrict__ out,
                                                  unsigned int* __restrict__ bar, int n) {
    __shared__ float4 sx[N4], sy[N4], sz[N4], sl[N4];   // 64 KB
    const int n4   = n >> 2;
    const int lane = threadIdx.x & 63;
    const int i0   = blockIdx.x * 16 + (threadIdx.x >> 6) * 2;
    const unsigned int nb = gridDim.x;
    unsigned int phase = 0;

    // predict: every block builds the full predicted-position copy in LDS
    // (no global exchange needed for iteration 1's rho).
    predict_to_lds(locs4, vel4, sx, sy, sz, n4, threadIdx.x, 512);
    __syncthreads();

    for (int it = 0; it < 3; ++it) {
        const bool last = (it == 2);

        // rho: LDS pred -> L[i0..i0+1] (global, device-coherent)
        rho_body2(sx, sy, sz, lam, n4, i0, lane);
        grid_barrier(bar, (++phase) * nb);

        // stage L into LDS
        for (int idx = threadIdx.x; idx < n4; idx += 512) sl[idx] = ((const float4*)lam)[idx];
        __syncthreads();

        // delta: LDS pred + LDS L -> new pred for own particles (global SoA);
        // on last iteration also emit out_pred and new_vel.
        delta_body2(sx, sy, sz, sl, px, py, pz,
                    last ? locs : nullptr, last ? out : nullptr, vnx, vny, vnz,
                    n4, i0, lane);
        grid_barrier(bar, (++phase) * nb);

        // re-stage updated pred into LDS (used by next rho, or by visc)
        for (int idx = threadIdx.x; idx < n4; idx += 512) {
            sx[idx] = ((const float4*)px)[idx];
            sy[idx] = ((const float4*)py)[idx];
            sz[idx] = ((const float4*)pz)[idx];
        }
        __syncthreads();
    }

    // ---- XSPH viscosity on final positions (pred already in sx/sy/sz) ----
    const float* fpx = (const float*)sx; const float* fpy = (const float*)sy; const float* fpz = (const float*)sz;
    const float xi0 = fpx[i0],   yi0 = fpy[i0],   zi0 = fpz[i0];
    const float xi1 = fpx[i0+1], yi1 = fpy[i0+1], zi1 = fpz[i0+1];
    const float vix0 = vnx[i0],   viy0 = vny[i0],   viz0 = vnz[i0];
    const float vix1 = vnx[i0+1], viy1 = vny[i0+1], viz1 = vnz[i0+1];
    float ws0=0.f, ax0=0.f, ay0=0.f, az0=0.f;
    float ws1=0.f, ax1=0.f, ay1=0.f, az1=0.f;
    const float4* vx4 = (const float4*)vnx;
    const float4* vy4 = (const float4*)vny;
    const float4* vz4 = (const float4*)vnz;
    for (int ch = 0; ch < 4; ++ch) {
        __syncthreads();
        for (int idx = threadIdx.x; idx < CH4; idx += 512) {
            sl[idx]         = vx4[ch*CH4+idx];
            sl[CH4+idx]     = vy4[ch*CH4+idx];
            sl[2*CH4+idx]   = vz4[ch*CH4+idx];
        }
        __syncthreads();
        for (int k = lane; k < CH4; k += 64) {
            float4 X = sx[ch*CH4+k], Y = sy[ch*CH4+k], Z = sz[ch*CH4+k];
            float4 VX = sl[k], VY = sl[CH4+k], VZ = sl[2*CH4+k];
#pragma unroll
            for (int c = 0; c < 4; ++c) {
                float xj = elem(X,c), yj = elem(Y,c), zj = elem(Z,c);
                float vxj = elem(VX,c), vyj = elem(VY,c), vzj = elem(VZ,c);
                {
                    float dx = xi0-xj, dy = yi0-yj, dz = zi0-zj;
                    float d2 = fmaf(dx,dx,EPS); d2 = fmaf(dy,dy,d2); d2 = fmaf(dz,dz,d2);
                    float t  = fmaxf(RADIUS - __builtin_amdgcn_sqrtf(d2), 0.f);
                    float w  = t*t*t;
                    ws0 += w;
                    ax0 = fmaf(w, vxj, ax0); ay0 = fmaf(w, vyj, ay0); az0 = fmaf(w, vzj, az0);
                }
                {
                    float dx = xi1-xj, dy = yi1-yj, dz = zi1-zj;
                    float d2 = fmaf(dx,dx,EPS); d2 = fmaf(dy,dy,d2); d2 = fmaf(dz,dz,d2);
                    float t  = fmaxf(RADIUS - __builtin_amdgcn_sqrtf(d2), 0.f);
                    float w  = t*t*t;
                    ws1 += w;
                    ax1 = fmaf(w, vxj, ax1); ay1 = fmaf(w, vyj, ay1); az1 = fmaf(w, vzj, az1);
                }
            }
        }
    }
    for (int off = 32; off > 0; off >>= 1) {
        ws0 += __shfl_down(ws0, off); ax0 += __shfl_down(ax0, off);
        ay0 += __shfl_down(ay0, off); az0 += __shfl_down(az0, off);
        ws1 += __shfl_down(ws1, off); ax1 += __shfl_down(ax1, off);
        ay1 += __shfl_down(ay1, off); az1 += __shfl_down(az1, off);
    }
    if (lane == 0) {
        constexpr float K = VISCOSITY * DT / DENSITY_REST;
        const float KC = K * SPIKY_C;   // C folded here
#pragma unroll
        for (int u = 0; u < 2; ++u) {
            int i = i0 + u;
            float vix = (u ? vix1 : vix0), viy = (u ? viy1 : viy0), viz = (u ? viz1 : viz0);
            float sw  = (u ? ws1 : ws0);
            float sax = (u ? ax1 : ax0), say = (u ? ay1 : ay0), saz = (u ? az1 : az0);
            float nvx = vix + KC * (sax - sw * vix);
            float nvy = viy + KC * (say - sw * viy);
            float nvz = viz + KC * (saz - sw * viz);
            float vv = sqrtf(nvx*nvx + nvy*nvy + nvz*nvz);
            float s  = fminf(MAX_VEL / (vv + 1e-4f), 1.0f);
            out[3*n + 3*i + 0] = nvx * s;
            out[3*n + 3*i + 1] = nvy * s;
            out[3*n + 3*i + 2] = nvz * s;
        }
    }
}

extern "C" void kernel_launch(void* const* d_in, const int* in_sizes, int n_in,
                              void* d_out, int out_size, void* d_ws, size_t ws_size,
                              hipStream_t stream) {
    const float* locs = (const float*)d_in[0];
    const float* vel  = (const float*)d_in[1];
    const float4* locs4 = (const float4*)locs;
    const float4* vel4  = (const float4*)vel;
    float* out = (float*)d_out;
    int n = in_sizes[0] / 3;

    float* w = (float*)d_ws;
    float* px  = w;        float* py  = px + n;   float* pz  = py + n;
    float* lam = pz + n;
    float* vnx = lam + n;  float* vny = vnx + n;  float* vnz = vny + n;
    unsigned int* bar = (unsigned int*)(w + 10 * n);   // 64B barrier region after arrays

    // zero the barrier counter (stream-ordered, graph-capturable)
    hipMemsetAsync((void*)bar, 0, 64, stream);

    int nb = n / 16;   // 8 waves/block, 2 particles/wave -> 256 blocks for n=4096

    void* args[] = { (void*)&locs4, (void*)&vel4, (void*)&locs,
                     (void*)&px, (void*)&py, (void*)&pz,
                     (void*)&lam,
                     (void*)&vnx, (void*)&vny, (void*)&vnz,
                     (void*)&out, (void*)&bar, (void*)&n };
    hipLaunchCooperativeKernel((void*)k_fused, dim3(nb), dim3(512), args, 0, stream);
}